// Round 5
// baseline (717.587 us; speedup 1.0000x reference)
//
#include <hip/hip_runtime.h>
#include <hip/hip_bf16.h>
#include <stdint.h>

#define DIM 128
#define HIDDEN 512
#define EPS 1e-5f
#define HC 32               // hidden chunk
#define NCHUNK (HIDDEN/HC)  // 16

typedef __attribute__((ext_vector_type(8))) short bf16x8;
typedef __attribute__((ext_vector_type(4))) float f32x4;

__device__ __forceinline__ unsigned short bf16_rn(float f) {
    unsigned u = __builtin_bit_cast(unsigned, f);
    unsigned r = u + 0x7FFFu + ((u >> 16) & 1u);
    return (unsigned short)(r >> 16);
}
__device__ __forceinline__ float bf16_f32(unsigned short h) {
    unsigned u = ((unsigned)h) << 16;
    return __builtin_bit_cast(float, u);
}
// packed RTNE bf16 convert: a -> low 16, b -> high 16 (v_cvt_pk_bf16_f32 via
// compiler path; __hip_bfloat162 is not trivially copyable -> use memcpy)
__device__ __forceinline__ unsigned pk_bf16(float a, float b) {
    float2 t; t.x = a; t.y = b;
    __hip_bfloat162 r = __float22bfloat162_rn(t);
    unsigned u;
    __builtin_memcpy(&u, &r, 4);
    return u;
}

// ---------------------------------------------------------------------------
// Prep: split w1 (512x128) and w2 (128x512) into hi/lo bf16 planes laid out in
// MFMA A-operand fragment order: value(frag fi, lane l, j) = W[t*16+(l&15)][ks*32+(l>>4)*8+j]
// w1f: fi = (p*32 + nt)*4 + ks   (nt: 32 hidden tiles, ks: 4 k-steps over DIM)
// w2f: fi = (p*8  + dt)*16 + ks  (dt: 8 out tiles,    ks: 16 k-steps over HIDDEN)
// ---------------------------------------------------------------------------
__global__ __launch_bounds__(256) void prep_weights(
    const float* __restrict__ w1, const float* __restrict__ w2,
    unsigned short* __restrict__ w1f, unsigned short* __restrict__ w2f) {
    int idx = blockIdx.x * 256 + threadIdx.x;   // 0 .. 262143
    int o = idx & 131071;
    int j = o & 7;
    int l = (o >> 3) & 63;
    int fi = o >> 9;
    if (idx < 131072) {
        int ks = fi & 3, t = (fi >> 2) & 31, p = fi >> 7;
        int row = t * 16 + (l & 15);
        int col = ks * 32 + (l >> 4) * 8 + j;
        float v = w1[row * DIM + col];
        unsigned short hi = bf16_rn(v);
        w1f[o] = p ? bf16_rn(v - bf16_f32(hi)) : hi;
    } else {
        int ks = fi & 15, t = (fi >> 4) & 7, p = fi >> 7;
        int row = t * 16 + (l & 15);
        int col = ks * 32 + (l >> 4) * 8 + j;
        float v = w2[row * HIDDEN + col];
        unsigned short hi = bf16_rn(v);
        w2f[o] = p ? bf16_rn(v - bf16_f32(hi)) : hi;
    }
}

// ---------------------------------------------------------------------------
// Fused LN -> Linear -> ReLU -> Linear. 4 waves/block, each wave owns 16
// tokens end-to-end (MT=1; small register state -> 4 waves/SIMD occupancy).
// No inter-wave communication; no __syncthreads.
// Both GEMMs computed transposed (weights as MFMA A-operand):
//   G1: D[n][m] = sum_k w1[n][k]*xn[m][k]   (acc col = token)
//   G2: D[d][m] = sum_k w2[d][k]*h[m][k]    (lane's 4 regs = 4 consecutive d)
// ---------------------------------------------------------------------------
__global__ __launch_bounds__(256, 4) void fused_mlp(
    const float* __restrict__ x,
    const unsigned short* __restrict__ w1f,
    const unsigned short* __restrict__ w2f,
    const float* __restrict__ b1, const float* __restrict__ b2,
    const float* __restrict__ wn, const float* __restrict__ bn,
    float* __restrict__ out) {

    __shared__ __align__(16) char smem_all[4 * 8192];
    const int tid  = threadIdx.x;
    const int wid  = tid >> 6;
    const int lane = tid & 63;
    const int g    = lane >> 4;    // k-group 0..3
    const int li   = lane & 15;
    char* smem = smem_all + wid * 8192;

    const int tok_base = blockIdx.x * 64 + wid * 16;

    // per-lane LN affine params (cols 2*lane, 2*lane+1), loaded once
    float2 wnv = *(const float2*)(wn + lane * 2);
    float2 bnv = *(const float2*)(bn + lane * 2);

    // A(xn) fragments for GEMM1, kept in registers the whole kernel:
    // [ks][plane] -> 32 VGPRs
    bf16x8 xf[4][2];

    // ---- Phase 1: LayerNorm + split + transpose (via wave-private LDS bounce)
    #pragma unroll 4
    for (int r = 0; r < 16; ++r) {
        int tok = tok_base + r;
        float2 xv = *(const float2*)(x + (size_t)tok * DIM + lane * 2);
        float s = xv.x + xv.y;
        float q = xv.x * xv.x + xv.y * xv.y;
        #pragma unroll
        for (int off = 32; off > 0; off >>= 1) {
            s += __shfl_xor(s, off, 64);
            q += __shfl_xor(q, off, 64);
        }
        float mean = s * (1.0f / 128.0f);
        float var  = q * (1.0f / 128.0f) - mean * mean;
        float rstd = rsqrtf(var + EPS);
        float y0 = (xv.x - mean) * rstd * wnv.x + bnv.x;
        float y1 = (xv.y - mean) * rstd * wnv.y + bnv.y;
        unsigned hiw = pk_bf16(y0, y1);
        float f0 = __builtin_bit_cast(float, hiw << 16);
        float f1 = __builtin_bit_cast(float, hiw & 0xFFFF0000u);
        unsigned low = pk_bf16(y0 - f0, y1 - f1);
        // bounce tile [16][128] bf16 per plane, XOR-swizzled rows
        int byte = (r * 256 + lane * 4) ^ ((r & 7) << 4);
        *(unsigned*)(smem + byte)        = hiw;
        *(unsigned*)(smem + 4096 + byte) = low;
    }
    #pragma unroll
    for (int ks = 0; ks < 4; ++ks) {
        #pragma unroll
        for (int p = 0; p < 2; ++p) {
            int byte = (li * 256 + ks * 64 + g * 16) ^ ((li & 7) << 4);
            xf[ks][p] = *(const bf16x8*)(smem + p * 4096 + byte);
        }
    }

    // ---- Phase 2: chunk loop over hidden (16 chunks of 32)
    f32x4 acc2[8];
    #pragma unroll
    for (int dt = 0; dt < 8; ++dt) acc2[dt] = (f32x4){0.f, 0.f, 0.f, 0.f};

    for (int c = 0; c < NCHUNK; ++c) {
        // --- GEMM1 (3-pass split) + bias + ReLU + split-store h
        #pragma unroll
        for (int ntl = 0; ntl < 2; ++ntl) {
            bf16x8 wfr[4][2];
            int ntg = c * 2 + ntl;
            #pragma unroll
            for (int ks = 0; ks < 4; ++ks) {
                #pragma unroll
                for (int p = 0; p < 2; ++p) {
                    size_t off = ((size_t)((p * 32 + ntg) * 4 + ks)) * 512 + lane * 8;
                    wfr[ks][p] = *(const bf16x8*)(w1f + off);
                }
            }
            f32x4 acc1 = (f32x4){0.f, 0.f, 0.f, 0.f};
            #pragma unroll
            for (int ks = 0; ks < 4; ++ks) {
                acc1 = __builtin_amdgcn_mfma_f32_16x16x32_bf16(wfr[ks][0], xf[ks][0], acc1, 0, 0, 0);
                acc1 = __builtin_amdgcn_mfma_f32_16x16x32_bf16(wfr[ks][0], xf[ks][1], acc1, 0, 0, 0);
                acc1 = __builtin_amdgcn_mfma_f32_16x16x32_bf16(wfr[ks][1], xf[ks][0], acc1, 0, 0, 0);
            }
            f32x4 b1v = *(const f32x4*)(b1 + c * HC + ntl * 16 + g * 4);
            unsigned hw[2], lw[2];
            #pragma unroll
            for (int rr = 0; rr < 2; ++rr) {
                float v0 = fmaxf(acc1[rr * 2]     + b1v[rr * 2],     0.f);
                float v1 = fmaxf(acc1[rr * 2 + 1] + b1v[rr * 2 + 1], 0.f);
                unsigned hww = pk_bf16(v0, v1);
                float f0 = __builtin_bit_cast(float, hww << 16);
                float f1 = __builtin_bit_cast(float, hww & 0xFFFF0000u);
                hw[rr] = hww;
                lw[rr] = pk_bf16(v0 - f0, v1 - f1);
            }
            // h tile [16][HC] bf16 per plane; lane writes 4 consecutive k
            int byte = (li * 64 + ntl * 32 + g * 8) ^ (((li >> 1) & 3) << 4);
            *(uint2*)(smem + byte)        = make_uint2(hw[0], hw[1]);
            *(uint2*)(smem + 2048 + byte) = make_uint2(lw[0], lw[1]);
        }
        // --- read h fragments (B-operand of GEMM2)
        bf16x8 hf[2];
        #pragma unroll
        for (int p = 0; p < 2; ++p) {
            int byte = (li * 64 + g * 16) ^ (((li >> 1) & 3) << 4);
            hf[p] = *(const bf16x8*)(smem + p * 2048 + byte);
        }
        // --- GEMM2 (3-pass split), accumulate C2^T
        #pragma unroll
        for (int dt = 0; dt < 8; ++dt) {
            size_t off0 = ((size_t)((0 * 8 + dt) * 16 + c)) * 512 + lane * 8;
            size_t off1 = ((size_t)((1 * 8 + dt) * 16 + c)) * 512 + lane * 8;
            bf16x8 w2hi = *(const bf16x8*)(w2f + off0);
            bf16x8 w2lo = *(const bf16x8*)(w2f + off1);
            acc2[dt] = __builtin_amdgcn_mfma_f32_16x16x32_bf16(w2hi, hf[0], acc2[dt], 0, 0, 0);
            acc2[dt] = __builtin_amdgcn_mfma_f32_16x16x32_bf16(w2hi, hf[1], acc2[dt], 0, 0, 0);
            acc2[dt] = __builtin_amdgcn_mfma_f32_16x16x32_bf16(w2lo, hf[0], acc2[dt], 0, 0, 0);
        }
    }

    // ---- Phase 3: epilogue, +b2, dwordx4 stores (lane holds 4 consecutive d)
    #pragma unroll
    for (int dt = 0; dt < 8; ++dt) {
        f32x4 b2v = *(const f32x4*)(b2 + dt * 16 + g * 4);
        f32x4 v = acc2[dt] + b2v;
        int tok = tok_base + li;
        *(f32x4*)(out + (size_t)tok * DIM + dt * 16 + g * 4) = v;
    }
}

extern "C" void kernel_launch(void* const* d_in, const int* in_sizes, int n_in,
                              void* d_out, int out_size, void* d_ws, size_t ws_size,
                              hipStream_t stream) {
    const float* x  = (const float*)d_in[0];
    const float* w1 = (const float*)d_in[1];
    const float* w2 = (const float*)d_in[2];
    const float* b1 = (const float*)d_in[3];
    const float* b2 = (const float*)d_in[4];
    const float* wn = (const float*)d_in[5];
    const float* bn = (const float*)d_in[6];
    float* out = (float*)d_out;

    unsigned short* w1f = (unsigned short*)d_ws;
    unsigned short* w2f = w1f + 131072;

    prep_weights<<<1024, 256, 0, stream>>>(w1, w2, w1f, w2f);
    fused_mlp<<<4096, 256, 0, stream>>>(x, w1f, w2f, b1, b2, wn, bn, out);
}

// Round 8
// 395.580 us; speedup vs baseline: 1.8140x; 1.8140x over previous
//
#include <hip/hip_runtime.h>
#include <hip/hip_bf16.h>
#include <stdint.h>

#define DIM 128
#define HIDDEN 512
#define EPS 1e-5f
#define NCHUNK 16   // 16 chunks x 32 hidden

typedef __attribute__((ext_vector_type(8))) short bf16x8;
typedef __attribute__((ext_vector_type(4))) float f32x4;

__device__ __forceinline__ unsigned short bf16_rn(float f) {
    unsigned u = __builtin_bit_cast(unsigned, f);
    unsigned r = u + 0x7FFFu + ((u >> 16) & 1u);
    return (unsigned short)(r >> 16);
}
__device__ __forceinline__ float bf16_f32(unsigned short h) {
    unsigned u = ((unsigned)h) << 16;
    return __builtin_bit_cast(float, u);
}
// packed RTNE bf16 convert: a -> low 16, b -> high 16 (v_cvt_pk_bf16_f32)
__device__ __forceinline__ unsigned pk_bf16(float a, float b) {
    float2 t; t.x = a; t.y = b;
    __hip_bfloat162 r = __float22bfloat162_rn(t);
    unsigned u;
    __builtin_memcpy(&u, &r, 4);
    return u;
}

// ---------------------------------------------------------------------------
// Prep (identical to the r2/r5 PASSING version): split w1 (512x128) and
// w2 (128x512) into hi/lo bf16 planes in MFMA A-operand fragment order:
//   value(frag fi, lane l, j) = W[t*16+(l&15)][ks*32+(l>>4)*8+j]
// w1f: fi = (p*32 + nt)*4 + ks   (nt: 32 hidden tiles, ks: 4 k-steps over DIM)
// w2f: fi = (p*8  + dt)*16 + ks  (dt: 8 out tiles,    ks: 16 k-steps over HIDDEN)
// Each fragment = 512 shorts = 1024 B, lane-linear (lane*8 shorts).
// ws usage: 2*262144 B = 524288 B exactly (proven within ws_size in r2/r5).
// ---------------------------------------------------------------------------
__global__ __launch_bounds__(256) void prep_weights(
    const float* __restrict__ w1, const float* __restrict__ w2,
    unsigned short* __restrict__ w1f, unsigned short* __restrict__ w2f) {
    int idx = blockIdx.x * 256 + threadIdx.x;   // 0 .. 262143
    int o = idx & 131071;
    int j = o & 7;
    int l = (o >> 3) & 63;
    int fi = o >> 9;
    if (idx < 131072) {
        int ks = fi & 3, t = (fi >> 2) & 31, p = fi >> 7;
        int row = t * 16 + (l & 15);
        int col = ks * 32 + (l >> 4) * 8 + j;
        float v = w1[row * DIM + col];
        unsigned short hi = bf16_rn(v);
        w1f[o] = p ? bf16_rn(v - bf16_f32(hi)) : hi;
    } else {
        int ks = fi & 15, t = (fi >> 4) & 7, p = fi >> 7;
        int row = t * 16 + (l & 15);
        int col = ks * 32 + (l >> 4) * 8 + j;
        float v = w2[row * HIDDEN + col];
        unsigned short hi = bf16_rn(v);
        w2f[o] = p ? bf16_rn(v - bf16_f32(hi)) : hi;
    }
}

// slot s (0..31) -> source fragment for chunk c
__device__ __forceinline__ const unsigned short* slot_src(
    const unsigned short* __restrict__ w1f,
    const unsigned short* __restrict__ w2f, int s, int c) {
    if (s < 16) {   // GEMM1 slot: s = ntl*8 + ks*2 + p
        int ntl = s >> 3, ks = (s >> 1) & 3, p = s & 1;
        return w1f + ((size_t)((p * 32 + c * 2 + ntl) * 4 + ks)) * 512;
    } else {        // GEMM2 slot: 16 + dt*2 + p
        int q = s - 16, dt = q >> 1, p = q & 1;
        return w2f + ((size_t)((p * 8 + dt) * 16 + c)) * 512;
    }
}

// ---------------------------------------------------------------------------
// Fused LN -> Linear -> ReLU -> Linear. 4 waves/block, wave owns 32 tokens.
// Weights shared block-wide via double-buffered LDS, REGISTER-staged
// (global->VGPR->ds_write_b128; T14 pattern, no global_load_lds):
//   prologue: load c0->rA; phase1(LN); ds_write rA->buf0; load c1->rB; barrier
//   body(c,cur,nxt): ds_write nxt->buf[(c+1)&1]; load c+2->cur;
//                    compute from buf[c&1]; barrier
// One barrier per chunk. Writes of buf[(c+1)&1] are safe: the barrier ending
// iteration c-1 guaranteed all waves finished READING that buffer.
// LDS: 2x32 KB weight dbuf + 4x4 KB h-bounce = 80 KB -> 2 blocks/CU.
// ---------------------------------------------------------------------------
__global__ __launch_bounds__(256, 2) void fused_mlp(
    const float* __restrict__ x,
    const unsigned short* __restrict__ w1f,
    const unsigned short* __restrict__ w2f,
    const float* __restrict__ b1, const float* __restrict__ b2,
    const float* __restrict__ wn, const float* __restrict__ bn,
    float* __restrict__ out) {

    __shared__ __align__(16) char lds[81920];
    const int tid  = threadIdx.x;
    const int wid  = tid >> 6;
    const int lane = tid & 63;
    const int g    = lane >> 4;    // k-group 0..3
    const int li   = lane & 15;
    char* hbase = lds + 65536 + wid * 4096;   // per-wave h bounce (2 planes x 2 KB)

    const int tok_base = blockIdx.x * 128 + wid * 32;

    bf16x8 rA[8], rB[8];
    auto load_chunk = [&](bf16x8 (&r)[8], int c) {
        #pragma unroll
        for (int i = 0; i < 8; ++i)
            r[i] = *(const bf16x8*)(slot_src(w1f, w2f, wid * 8 + i, c) + lane * 8);
    };
    auto write_chunk = [&](bf16x8 (&r)[8], char* buf) {
        #pragma unroll
        for (int i = 0; i < 8; ++i)
            *(bf16x8*)(buf + (wid * 8 + i) * 1024 + lane * 16) = r[i];
    };

    // issue chunk-0 weight loads immediately; latency hides under phase 1
    load_chunk(rA, 0);

    // ---- Phase 1: direct-load LN -> in-register split into MFMA fragments.
    // Lane (li,g) owns token (tok_base + mt*16 + li), cols {ks*32 + g*8 + ...}.
    // Affine (wn,bn) applied in f32 here, exactly as the passing r5 version.
    bf16x8 xf[2][4][2];
    {
        f32x4 wnv[4][2], bnv[4][2];
        #pragma unroll
        for (int ks = 0; ks < 4; ++ks) {
            #pragma unroll
            for (int h = 0; h < 2; ++h) {
                wnv[ks][h] = *(const f32x4*)(wn + ks * 32 + g * 8 + h * 4);
                bnv[ks][h] = *(const f32x4*)(bn + ks * 32 + g * 8 + h * 4);
            }
        }
        #pragma unroll
        for (int mt = 0; mt < 2; ++mt) {
            const float* xr = x + (size_t)(tok_base + mt * 16 + li) * DIM;
            f32x4 v[4][2];
            float s = 0.f, q = 0.f;
            #pragma unroll
            for (int ks = 0; ks < 4; ++ks) {
                #pragma unroll
                for (int h = 0; h < 2; ++h) {
                    v[ks][h] = *(const f32x4*)(xr + ks * 32 + g * 8 + h * 4);
                    #pragma unroll
                    for (int j = 0; j < 4; ++j) {
                        s += v[ks][h][j];
                        q += v[ks][h][j] * v[ks][h][j];
                    }
                }
            }
            s += __shfl_xor(s, 16, 64); q += __shfl_xor(q, 16, 64);
            s += __shfl_xor(s, 32, 64); q += __shfl_xor(q, 32, 64);
            float mean = s * (1.0f / 128.0f);
            float var  = q * (1.0f / 128.0f) - mean * mean;
            float rstd = rsqrtf(var + EPS);
            #pragma unroll
            for (int ks = 0; ks < 4; ++ks) {
                unsigned hw[4], lw[4];
                #pragma unroll
                for (int h = 0; h < 2; ++h) {
                    #pragma unroll
                    for (int jj = 0; jj < 2; ++jj) {
                        float y0 = (v[ks][h][jj * 2]     - mean) * rstd * wnv[ks][h][jj * 2]     + bnv[ks][h][jj * 2];
                        float y1 = (v[ks][h][jj * 2 + 1] - mean) * rstd * wnv[ks][h][jj * 2 + 1] + bnv[ks][h][jj * 2 + 1];
                        unsigned hiw = pk_bf16(y0, y1);
                        float f0 = __builtin_bit_cast(float, hiw << 16);
                        float f1 = __builtin_bit_cast(float, hiw & 0xFFFF0000u);
                        hw[h * 2 + jj] = hiw;
                        lw[h * 2 + jj] = pk_bf16(y0 - f0, y1 - f1);
                    }
                }
                __builtin_memcpy(&xf[mt][ks][0], hw, 16);
                __builtin_memcpy(&xf[mt][ks][1], lw, 16);
            }
        }
    }

    // stage chunk 0 into buf0 (waits rA's loads), prefetch chunk 1
    write_chunk(rA, lds);
    load_chunk(rB, 1);
    __syncthreads();   // buf0 visible to all waves

    f32x4 acc2[8][2];
    #pragma unroll
    for (int dt = 0; dt < 8; ++dt)
        #pragma unroll
        for (int mt = 0; mt < 2; ++mt)
            acc2[dt][mt] = (f32x4){0.f, 0.f, 0.f, 0.f};

    auto body = [&](int c, bf16x8 (&cur)[8], bf16x8 (&nxt)[8]) {
        if (c + 1 < NCHUNK) write_chunk(nxt, lds + ((c + 1) & 1) * 32768);
        if (c + 2 < NCHUNK) load_chunk(cur, c + 2);
        char* buf = lds + (c & 1) * 32768;

        // --- GEMM1 (3-pass split) + bias + ReLU + split-store h
        #pragma unroll
        for (int ntl = 0; ntl < 2; ++ntl) {
            bf16x8 wfr[4][2];
            #pragma unroll
            for (int ks = 0; ks < 4; ++ks)
                #pragma unroll
                for (int p = 0; p < 2; ++p)
                    wfr[ks][p] = *(const bf16x8*)(buf + (ntl * 8 + ks * 2 + p) * 1024 + lane * 16);
            f32x4 acc1[2];
            acc1[0] = (f32x4){0.f, 0.f, 0.f, 0.f};
            acc1[1] = (f32x4){0.f, 0.f, 0.f, 0.f};
            #pragma unroll
            for (int ks = 0; ks < 4; ++ks) {
                #pragma unroll
                for (int mt = 0; mt < 2; ++mt) {
                    acc1[mt] = __builtin_amdgcn_mfma_f32_16x16x32_bf16(wfr[ks][0], xf[mt][ks][0], acc1[mt], 0, 0, 0);
                    acc1[mt] = __builtin_amdgcn_mfma_f32_16x16x32_bf16(wfr[ks][0], xf[mt][ks][1], acc1[mt], 0, 0, 0);
                    acc1[mt] = __builtin_amdgcn_mfma_f32_16x16x32_bf16(wfr[ks][1], xf[mt][ks][0], acc1[mt], 0, 0, 0);
                }
            }
            f32x4 b1v = *(const f32x4*)(b1 + c * 32 + ntl * 16 + g * 4);
            #pragma unroll
            for (int mt = 0; mt < 2; ++mt) {
                unsigned hw[2], lw[2];
                #pragma unroll
                for (int rr = 0; rr < 2; ++rr) {
                    float v0 = fmaxf(acc1[mt][rr * 2]     + b1v[rr * 2],     0.f);
                    float v1 = fmaxf(acc1[mt][rr * 2 + 1] + b1v[rr * 2 + 1], 0.f);
                    unsigned hww = pk_bf16(v0, v1);
                    float f0 = __builtin_bit_cast(float, hww << 16);
                    float f1 = __builtin_bit_cast(float, hww & 0xFFFF0000u);
                    hw[rr] = hww;
                    lw[rr] = pk_bf16(v0 - f0, v1 - f1);
                }
                int row  = mt * 16 + li;
                int byte = (row * 64 + ntl * 32 + g * 8) ^ (((row >> 1) & 3) << 4);
                *(uint2*)(hbase + byte)        = make_uint2(hw[0], hw[1]);
                *(uint2*)(hbase + 2048 + byte) = make_uint2(lw[0], lw[1]);
            }
        }
        // --- read h fragments (B-operand of GEMM2)
        bf16x8 hf[2][2];
        #pragma unroll
        for (int mt = 0; mt < 2; ++mt) {
            #pragma unroll
            for (int p = 0; p < 2; ++p) {
                int row  = mt * 16 + li;
                int byte = (row * 64 + g * 16) ^ (((row >> 1) & 3) << 4);
                hf[mt][p] = *(const bf16x8*)(hbase + p * 2048 + byte);
            }
        }
        // --- GEMM2 (3-pass split), accumulate C2^T
        #pragma unroll
        for (int dt = 0; dt < 8; ++dt) {
            const bf16x8 w2hi = *(const bf16x8*)(buf + (16 + dt * 2 + 0) * 1024 + lane * 16);
            const bf16x8 w2lo = *(const bf16x8*)(buf + (16 + dt * 2 + 1) * 1024 + lane * 16);
            #pragma unroll
            for (int mt = 0; mt < 2; ++mt) {
                acc2[dt][mt] = __builtin_amdgcn_mfma_f32_16x16x32_bf16(w2hi, hf[mt][0], acc2[dt][mt], 0, 0, 0);
                acc2[dt][mt] = __builtin_amdgcn_mfma_f32_16x16x32_bf16(w2hi, hf[mt][1], acc2[dt][mt], 0, 0, 0);
                acc2[dt][mt] = __builtin_amdgcn_mfma_f32_16x16x32_bf16(w2lo, hf[mt][0], acc2[dt][mt], 0, 0, 0);
            }
        }
        __syncthreads();   // all waves done reading buf[c&1]; buf[(c+1)&1] staged
    };

    for (int cc = 0; cc < NCHUNK; cc += 2) {
        body(cc,     rA, rB);
        body(cc + 1, rB, rA);
    }

    // ---- Phase 3: epilogue, +b2, dwordx4 stores (lane holds 4 consecutive d)
    #pragma unroll
    for (int dt = 0; dt < 8; ++dt) {
        f32x4 b2v = *(const f32x4*)(b2 + dt * 16 + g * 4);
        #pragma unroll
        for (int mt = 0; mt < 2; ++mt) {
            f32x4 v = acc2[dt][mt] + b2v;
            int tok = tok_base + mt * 16 + li;
            *(f32x4*)(out + (size_t)tok * DIM + dt * 16 + g * 4) = v;
        }
    }
}

extern "C" void kernel_launch(void* const* d_in, const int* in_sizes, int n_in,
                              void* d_out, int out_size, void* d_ws, size_t ws_size,
                              hipStream_t stream) {
    const float* x  = (const float*)d_in[0];
    const float* w1 = (const float*)d_in[1];
    const float* w2 = (const float*)d_in[2];
    const float* b1 = (const float*)d_in[3];
    const float* b2 = (const float*)d_in[4];
    const float* wn = (const float*)d_in[5];
    const float* bn = (const float*)d_in[6];
    float* out = (float*)d_out;

    unsigned short* w1f = (unsigned short*)d_ws;                 // 256 KB
    unsigned short* w2f = w1f + 131072;                          // 256 KB

    prep_weights<<<1024, 256, 0, stream>>>(w1, w2, w1f, w2f);
    fused_mlp<<<2048, 256, 0, stream>>>(x, w1f, w2f, b1, b2, wn, bn, out);
}

// Round 9
// 289.239 us; speedup vs baseline: 2.4809x; 1.3677x over previous
//
#include <hip/hip_runtime.h>
#include <hip/hip_bf16.h>
#include <stdint.h>

#define DIM 128
#define HIDDEN 512
#define EPS 1e-5f
#define NCHUNK 16   // 16 chunks x 32 hidden

typedef __attribute__((ext_vector_type(8))) short bf16x8;
typedef __attribute__((ext_vector_type(4))) float f32x4;

__device__ __forceinline__ unsigned short bf16_rn(float f) {
    unsigned u = __builtin_bit_cast(unsigned, f);
    unsigned r = u + 0x7FFFu + ((u >> 16) & 1u);
    return (unsigned short)(r >> 16);
}
// packed RTNE bf16 convert: a -> low 16, b -> high 16 (v_cvt_pk_bf16_f32)
__device__ __forceinline__ unsigned pk_bf16(float a, float b) {
    float2 t; t.x = a; t.y = b;
    __hip_bfloat162 r = __float22bfloat162_rn(t);
    unsigned u;
    __builtin_memcpy(&u, &r, 4);
    return u;
}

// async global->LDS, 16B per lane: dest = ldsbase + lane*16 (wave-uniform base,
// linear dest — the guide-verified m97 pattern; source is lane-linear too)
__device__ __forceinline__ void gload_lds16(const void* g, void* l) {
    __builtin_amdgcn_global_load_lds(
        (const __attribute__((address_space(1))) unsigned int*)g,
        (__attribute__((address_space(3))) unsigned int*)l, 16, 0, 0);
}

// ---------------------------------------------------------------------------
// Prep: single-plane bf16 (1-pass scheme) in MFMA A-operand fragment order:
//   value(frag fi, lane l, j) = W[t*16+(l&15)][ks*32+(l>>4)*8+j]
// w1f: fi = nt*4 + ks   (nt: 32 hidden tiles, ks: 4 k-steps over DIM)  128 KB
// w2f: fi = dt*16 + ks  (dt: 8 out tiles,   ks: 16 k-steps over HIDDEN) 128 KB
// Each fragment = 512 shorts = 1024 B, lane-linear (lane*8 shorts).
// ws usage: 256 KB (< 512 KB proven safe in r2/r5/r8).
// ---------------------------------------------------------------------------
__global__ __launch_bounds__(256) void prep_weights(
    const float* __restrict__ w1, const float* __restrict__ w2,
    unsigned short* __restrict__ w1f, unsigned short* __restrict__ w2f) {
    int idx = blockIdx.x * 256 + threadIdx.x;   // 0 .. 131071
    int o = idx & 65535;
    int j = o & 7;
    int l = (o >> 3) & 63;
    int fi = o >> 9;
    if (idx < 65536) {
        int ks = fi & 3, t = fi >> 2;
        int row = t * 16 + (l & 15);
        int col = ks * 32 + (l >> 4) * 8 + j;
        w1f[o] = bf16_rn(w1[row * DIM + col]);
    } else {
        int ks = fi & 15, t = fi >> 4;
        int row = t * 16 + (l & 15);
        int col = ks * 32 + (l >> 4) * 8 + j;
        w2f[o] = bf16_rn(w2[row * HIDDEN + col]);
    }
}

// slot s (0..15) -> source fragment for chunk c
__device__ __forceinline__ const unsigned short* slot_src(
    const unsigned short* __restrict__ w1f,
    const unsigned short* __restrict__ w2f, int s, int c) {
    if (s < 8) {    // GEMM1 slot: s = ntl*4 + ks
        int ntl = s >> 2, ks = s & 3;
        return w1f + ((size_t)((c * 2 + ntl) * 4 + ks)) * 512;
    } else {        // GEMM2 slot: 8 + dt
        int dt = s - 8;
        return w2f + ((size_t)(dt * 16 + c)) * 512;
    }
}

// stage one 16 KB chunk (16 slots x 1 KB); wave wid stages slots [wid*4, wid*4+4)
__device__ __forceinline__ void stage_chunk(
    const unsigned short* __restrict__ w1f,
    const unsigned short* __restrict__ w2f,
    char* buf, int c, int wid, int lane) {
    #pragma unroll
    for (int i = 0; i < 4; ++i) {
        const int s = wid * 4 + i;
        gload_lds16(slot_src(w1f, w2f, s, c) + lane * 8, buf + s * 1024);
    }
}

// ---------------------------------------------------------------------------
// Fused LN -> Linear -> ReLU -> Linear, plain bf16 1-pass MFMA (both GEMMs).
// 4 waves/block, wave owns 32 tokens. Weights shared block-wide via
// double-buffered LDS, staged with global_load_lds (async DMA):
//   prologue: stage(buf0, 0); phase1(LN); barrier (drains vmcnt);
//   loop c: stage(buf[(c+1)&1], c+1); compute from buf[c&1]; barrier;
// No wave reads buf[(c+1)&1] until after the barrier ending iter c -> safe.
// LDS: 2x16 KB weight dbuf + 4x2 KB h-bounce = 40 KB -> 3 blocks/CU (VGPR-capped).
// ---------------------------------------------------------------------------
__global__ __launch_bounds__(256, 3) void fused_mlp(
    const float* __restrict__ x,
    const unsigned short* __restrict__ w1f,
    const unsigned short* __restrict__ w2f,
    const float* __restrict__ b1, const float* __restrict__ b2,
    const float* __restrict__ wn, const float* __restrict__ bn,
    float* __restrict__ out) {

    __shared__ __align__(16) char lds[40960];
    const int tid  = threadIdx.x;
    const int wid  = tid >> 6;
    const int lane = tid & 63;
    const int g    = lane >> 4;    // k-group 0..3
    const int li   = lane & 15;
    char* hbase = lds + 32768 + wid * 2048;   // per-wave h bounce (single plane)

    const int tok_base = blockIdx.x * 128 + wid * 32;

    // issue chunk-0 weight DMA immediately; latency hides under phase 1
    stage_chunk(w1f, w2f, lds, 0, wid, lane);

    // ---- Phase 1: direct-load LN -> in-register bf16 MFMA fragments.
    // Lane (li,g) owns token (tok_base + mt*16 + li), cols {ks*32 + g*8 + j}.
    bf16x8 xf[2][4];
    {
        f32x4 wnv[4][2], bnv[4][2];
        #pragma unroll
        for (int ks = 0; ks < 4; ++ks) {
            #pragma unroll
            for (int h = 0; h < 2; ++h) {
                wnv[ks][h] = *(const f32x4*)(wn + ks * 32 + g * 8 + h * 4);
                bnv[ks][h] = *(const f32x4*)(bn + ks * 32 + g * 8 + h * 4);
            }
        }
        #pragma unroll
        for (int mt = 0; mt < 2; ++mt) {
            const float* xr = x + (size_t)(tok_base + mt * 16 + li) * DIM;
            f32x4 v[4][2];
            float s = 0.f, q = 0.f;
            #pragma unroll
            for (int ks = 0; ks < 4; ++ks) {
                #pragma unroll
                for (int h = 0; h < 2; ++h) {
                    v[ks][h] = *(const f32x4*)(xr + ks * 32 + g * 8 + h * 4);
                    #pragma unroll
                    for (int j = 0; j < 4; ++j) {
                        s += v[ks][h][j];
                        q += v[ks][h][j] * v[ks][h][j];
                    }
                }
            }
            s += __shfl_xor(s, 16, 64); q += __shfl_xor(q, 16, 64);
            s += __shfl_xor(s, 32, 64); q += __shfl_xor(q, 32, 64);
            float mean = s * (1.0f / 128.0f);
            float var  = q * (1.0f / 128.0f) - mean * mean;
            float rstd = rsqrtf(var + EPS);
            #pragma unroll
            for (int ks = 0; ks < 4; ++ks) {
                unsigned hw[4];
                #pragma unroll
                for (int h = 0; h < 2; ++h) {
                    #pragma unroll
                    for (int jj = 0; jj < 2; ++jj) {
                        float y0 = (v[ks][h][jj * 2]     - mean) * rstd * wnv[ks][h][jj * 2]     + bnv[ks][h][jj * 2];
                        float y1 = (v[ks][h][jj * 2 + 1] - mean) * rstd * wnv[ks][h][jj * 2 + 1] + bnv[ks][h][jj * 2 + 1];
                        hw[h * 2 + jj] = pk_bf16(y0, y1);
                    }
                }
                __builtin_memcpy(&xf[mt][ks], hw, 16);
            }
        }
    }

    __syncthreads();   // drains vmcnt -> chunk-0 weights resident in buf0

    f32x4 acc2[8][2];
    #pragma unroll
    for (int dt = 0; dt < 8; ++dt)
        #pragma unroll
        for (int mt = 0; mt < 2; ++mt)
            acc2[dt][mt] = (f32x4){0.f, 0.f, 0.f, 0.f};

    for (int c = 0; c < NCHUNK; ++c) {
        char* buf = lds + (c & 1) * 16384;
        if (c + 1 < NCHUNK)
            stage_chunk(w1f, w2f, lds + ((c + 1) & 1) * 16384, c + 1, wid, lane);

        // --- GEMM1 (1-pass) + bias + ReLU + store h (single bf16 plane)
        #pragma unroll
        for (int ntl = 0; ntl < 2; ++ntl) {
            bf16x8 wfr[4];
            #pragma unroll
            for (int ks = 0; ks < 4; ++ks)
                wfr[ks] = *(const bf16x8*)(buf + (ntl * 4 + ks) * 1024 + lane * 16);
            f32x4 acc1[2];
            acc1[0] = (f32x4){0.f, 0.f, 0.f, 0.f};
            acc1[1] = (f32x4){0.f, 0.f, 0.f, 0.f};
            #pragma unroll
            for (int ks = 0; ks < 4; ++ks) {
                #pragma unroll
                for (int mt = 0; mt < 2; ++mt)
                    acc1[mt] = __builtin_amdgcn_mfma_f32_16x16x32_bf16(wfr[ks], xf[mt][ks], acc1[mt], 0, 0, 0);
            }
            f32x4 b1v = *(const f32x4*)(b1 + c * 32 + ntl * 16 + g * 4);
            #pragma unroll
            for (int mt = 0; mt < 2; ++mt) {
                unsigned hw[2];
                #pragma unroll
                for (int rr = 0; rr < 2; ++rr) {
                    float v0 = fmaxf(acc1[mt][rr * 2]     + b1v[rr * 2],     0.f);
                    float v1 = fmaxf(acc1[mt][rr * 2 + 1] + b1v[rr * 2 + 1], 0.f);
                    hw[rr] = pk_bf16(v0, v1);
                }
                int row  = mt * 16 + li;
                int byte = (row * 64 + ntl * 32 + g * 8) ^ (((row >> 1) & 3) << 4);
                *(uint2*)(hbase + byte) = make_uint2(hw[0], hw[1]);
            }
        }
        // --- read h fragments (B-operand of GEMM2)
        bf16x8 hf[2];
        #pragma unroll
        for (int mt = 0; mt < 2; ++mt) {
            int row  = mt * 16 + li;
            int byte = (row * 64 + g * 16) ^ (((row >> 1) & 3) << 4);
            hf[mt] = *(const bf16x8*)(hbase + byte);
        }
        // --- GEMM2 (1-pass), accumulate C2^T
        #pragma unroll
        for (int dt = 0; dt < 8; ++dt) {
            const bf16x8 w2v = *(const bf16x8*)(buf + (8 + dt) * 1024 + lane * 16);
            #pragma unroll
            for (int mt = 0; mt < 2; ++mt)
                acc2[dt][mt] = __builtin_amdgcn_mfma_f32_16x16x32_bf16(w2v, hf[mt], acc2[dt][mt], 0, 0, 0);
        }
        __syncthreads();   // waves done with buf[c&1]; staging of c+1 drained
    }

    // ---- Phase 3: epilogue, +b2, dwordx4 stores (lane holds 4 consecutive d)
    #pragma unroll
    for (int dt = 0; dt < 8; ++dt) {
        f32x4 b2v = *(const f32x4*)(b2 + dt * 16 + g * 4);
        #pragma unroll
        for (int mt = 0; mt < 2; ++mt) {
            f32x4 v = acc2[dt][mt] + b2v;
            int tok = tok_base + mt * 16 + li;
            *(f32x4*)(out + (size_t)tok * DIM + dt * 16 + g * 4) = v;
        }
    }
}

extern "C" void kernel_launch(void* const* d_in, const int* in_sizes, int n_in,
                              void* d_out, int out_size, void* d_ws, size_t ws_size,
                              hipStream_t stream) {
    const float* x  = (const float*)d_in[0];
    const float* w1 = (const float*)d_in[1];
    const float* w2 = (const float*)d_in[2];
    const float* b1 = (const float*)d_in[3];
    const float* b2 = (const float*)d_in[4];
    const float* wn = (const float*)d_in[5];
    const float* bn = (const float*)d_in[6];
    float* out = (float*)d_out;

    unsigned short* w1f = (unsigned short*)d_ws;                 // 128 KB
    unsigned short* w2f = w1f + 65536;                           // 128 KB

    prep_weights<<<512, 256, 0, stream>>>(w1, w2, w1f, w2f);
    fused_mlp<<<2048, 256, 0, stream>>>(x, w1f, w2f, b1, b2, wn, bn, out);
}